// Round 1
// baseline (687.340 us; speedup 1.0000x reference)
//
#include <hip/hip_runtime.h>

typedef __attribute__((ext_vector_type(8))) __bf16 bf16x8;
typedef __attribute__((ext_vector_type(4))) float f32x4;
typedef __attribute__((ext_vector_type(8))) unsigned short u16x8;

#define LOG2E 1.44269504088896340736f

__device__ __forceinline__ unsigned short f2bf(float f){
  union { float f; unsigned u; } v; v.f = f;
  unsigned r = v.u + 0x7FFFu + ((v.u >> 16) & 1u);
  return (unsigned short)(r >> 16);
}
__device__ __forceinline__ float bf2f(unsigned short u){
  union { unsigned u; float f; } v; v.u = ((unsigned)u) << 16;
  return v.f;
}

typedef const unsigned __attribute__((address_space(1)))* gas_ptr;
typedef unsigned __attribute__((address_space(3)))* las_ptr;

__device__ __forceinline__ void gload_lds16(const void* g, void* l){
  __builtin_amdgcn_global_load_lds((gas_ptr)g, (las_ptr)l, 16, 0, 0);
}

// ---------------- f32 -> bf16 conversion ----------------
__global__ __launch_bounds__(256) void cvt_f32_bf16(const float* __restrict__ in,
                                                    unsigned short* __restrict__ out){
  size_t i = ((size_t)blockIdx.x * 256 + threadIdx.x) * 4;
  float4 vv = *(const float4*)(in + i);
  ushort4 o;
  o.x = f2bf(vv.x); o.y = f2bf(vv.y); o.z = f2bf(vv.z); o.w = f2bf(vv.w);
  *(ushort4*)(out + i) = o;
}

// ---------------- GEMM: C[M,N] = A[M,K] * B[N,K]^T  (m97 structure) ----------------
template<bool OUT_BF16>
__global__ __launch_bounds__(256) void gemm_bt(const unsigned short* __restrict__ A,
                                               const unsigned short* __restrict__ B,
                                               void* __restrict__ Cv,
                                               int M, int N, int K){
  __shared__ unsigned short As[128 * 32];
  __shared__ unsigned short Bs[128 * 32];
  const int tid = threadIdx.x;
  const int l = tid & 63, w = tid >> 6;
  const int lq = l & 15, lg = l >> 4;
  const int wr = w >> 1, wc = w & 1;
  const int br = blockIdx.y, bc = blockIdx.x;

  f32x4 acc[4][4] = {};
  const size_t Abase = (size_t)br * 128 * K;
  const size_t Bbase = (size_t)bc * 128 * K;

  for (int k0 = 0; k0 < K; k0 += 32){
    __syncthreads();
#pragma unroll
    for (int c = 0; c < 2; ++c){
      int off = c * 4096 + w * 1024 + l * 16;   // byte offset into 8KB tile
      int row = off >> 6, colb = off & 63;
      gload_lds16((const char*)(A + Abase + (size_t)row * K + k0) + colb,
                  (char*)As + c * 4096 + w * 1024);
      gload_lds16((const char*)(B + Bbase + (size_t)row * K + k0) + colb,
                  (char*)Bs + c * 4096 + w * 1024);
    }
    __syncthreads();

    bf16x8 af[4], bfr[4];
#pragma unroll
    for (int m = 0; m < 4; ++m)
      af[m] = *(const bf16x8*)(As + (wr * 64 + m * 16 + lq) * 32 + lg * 8);
#pragma unroll
    for (int n = 0; n < 4; ++n)
      bfr[n] = *(const bf16x8*)(Bs + (wc * 64 + n * 16 + lq) * 32 + lg * 8);
#pragma unroll
    for (int m = 0; m < 4; ++m)
#pragma unroll
      for (int n = 0; n < 4; ++n)
        acc[m][n] = __builtin_amdgcn_mfma_f32_16x16x32_bf16(af[m], bfr[n], acc[m][n], 0, 0, 0);
  }

  const int r0 = br * 128 + wr * 64 + lg * 4;
  const int c0 = bc * 128 + wc * 64 + lq;
#pragma unroll
  for (int m = 0; m < 4; ++m)
#pragma unroll
    for (int n = 0; n < 4; ++n)
#pragma unroll
      for (int j = 0; j < 4; ++j){
        size_t row = (size_t)(r0 + m * 16 + j);
        int col = c0 + n * 16;
        if (OUT_BF16)
          ((unsigned short*)Cv)[row * N + col] = f2bf(acc[m][n][j]);
        else
          ((float*)Cv)[row * N + col] = acc[m][n][j];
      }
}

// ---------------- RoPE (in-place on bf16 Q and K, layout [B*S][NH*HD]) ----------------
__global__ __launch_bounds__(256) void rope_kernel(unsigned short* __restrict__ q,
                                                   unsigned short* __restrict__ k,
                                                   const float* __restrict__ fc,
                                                   const float* __restrict__ fs){
  int tid = blockIdx.x * 256 + threadIdx.x;    // 0 .. 2097151
  int col8 = tid & 255;                        // 256 ushort8 per row
  int row = tid >> 8;                          // b*S + s
  int s = row & 2047;
  int i0 = (col8 & 15) * 4;                    // pair index base within head
  size_t eo = (size_t)row * 2048 + (size_t)(col8 >> 4) * 128 + (size_t)(col8 & 15) * 8;
  float4 c = *(const float4*)(fc + (size_t)s * 64 + i0);
  float4 sn = *(const float4*)(fs + (size_t)s * 64 + i0);
  float cs[4] = {c.x, c.y, c.z, c.w};
  float ss[4] = {sn.x, sn.y, sn.z, sn.w};
  u16x8 qv = *(const u16x8*)(q + eo);
  u16x8 kv = *(const u16x8*)(k + eo);
  u16x8 qo, ko;
#pragma unroll
  for (int p2 = 0; p2 < 4; ++p2){
    float a = bf2f(qv[2 * p2]), b = bf2f(qv[2 * p2 + 1]);
    qo[2 * p2]     = f2bf(a * cs[p2] - b * ss[p2]);
    qo[2 * p2 + 1] = f2bf(a * ss[p2] + b * cs[p2]);
    a = bf2f(kv[2 * p2]); b = bf2f(kv[2 * p2 + 1]);
    ko[2 * p2]     = f2bf(a * cs[p2] - b * ss[p2]);
    ko[2 * p2 + 1] = f2bf(a * ss[p2] + b * cs[p2]);
  }
  *(u16x8*)(q + eo) = qo;
  *(u16x8*)(k + eo) = ko;
}

// ---------------- Flash attention (causal), Q/K/V layout [B,S,NH,HD] ----------------
__global__ __launch_bounds__(256) void attn_fwd(const unsigned short* __restrict__ Q,
                                                const unsigned short* __restrict__ K,
                                                const unsigned short* __restrict__ V,
                                                unsigned short* __restrict__ O){
  __shared__ unsigned short Ks[64 * 128];     // [kv][d], XOR-swizzled rows
  __shared__ unsigned short Vt[128 * 64];     // [d][kv], XOR-swizzled rows
  __shared__ unsigned short Pl[4][16 * 72];   // per-wave P, row stride 72 (16B-aligned)

  const int tid = threadIdx.x;
  const int l = tid & 63, wid = tid >> 6;
  const int lq = l & 15, lg = l >> 4;
  const int bh = blockIdx.x & 63;
  const int qt = 31 - (blockIdx.x >> 6);      // long blocks dispatch first
  const int b = bh >> 4, h = bh & 15;
  const int q0 = qt * 64;
  const float scale = 0.08838834764831845f;   // 1/sqrt(128)

  // Q fragments, held in registers for the whole block
  const unsigned short* qptr = Q + ((size_t)b * 2048 + q0 + wid * 16 + lq) * 2048 + (size_t)h * 128;
  bf16x8 qf[4];
#pragma unroll
  for (int ks = 0; ks < 4; ++ks)
    qf[ks] = *(const bf16x8*)(qptr + ks * 32 + lg * 8);

  const f32x4 zero4 = {0.f, 0.f, 0.f, 0.f};
  float mrow[4], lrow[4];
  f32x4 oacc[8];
#pragma unroll
  for (int j = 0; j < 4; ++j){ mrow[j] = -3.0e38f; lrow[j] = 0.f; }
#pragma unroll
  for (int n = 0; n < 8; ++n) oacc[n] = zero4;

  const int nkt = qt + 1;
  for (int kt = 0; kt < nkt; ++kt){
    __syncthreads();
    const size_t kvbase = ((size_t)b * 2048 + kt * 64) * 2048 + (size_t)h * 128;

    // stage K tile [64][128] via global_load_lds, source pre-swizzled
#pragma unroll
    for (int c = 0; c < 4; ++c){
      int off = c * 4096 + wid * 1024 + l * 16;
      int row = off >> 8, colb = off & 255;
      int colbs = colb ^ ((row & 7) << 4);
      gload_lds16((const char*)(K + kvbase + (size_t)row * 2048) + colbs,
                  (char*)Ks + c * 4096 + wid * 1024);
    }
    // stage V transposed into Vt[d][kv] via registers (swizzled writes)
    {
      const int dblk = tid >> 4, kvp0 = tid & 15;
#pragma unroll
      for (int a2 = 0; a2 < 2; ++a2){
        int kv = 2 * (kvp0 + 16 * a2);
        const unsigned short* vp = V + kvbase + (size_t)kv * 2048 + dblk * 8;
        u16x8 r0 = *(const u16x8*)vp;
        u16x8 r1 = *(const u16x8*)(vp + 2048);
#pragma unroll
        for (int j = 0; j < 8; ++j){
          int d = dblk * 8 + j;
          unsigned val = (unsigned)r0[j] | ((unsigned)r1[j] << 16);
          *(unsigned*)((char*)Vt + d * 128 + ((kv * 2) ^ ((d & 7) << 4))) = val;
        }
      }
    }
    __syncthreads();

    // QK^T: S[q][kv], wave owns 16 q-rows x 64 kv-cols
    f32x4 sacc[4];
#pragma unroll
    for (int n = 0; n < 4; ++n){
      sacc[n] = zero4;
#pragma unroll
      for (int ks = 0; ks < 4; ++ks){
        int row = n * 16 + lq;
        bf16x8 kf = *(const bf16x8*)((const char*)Ks + row * 256 +
                                     ((ks * 64 + lg * 16) ^ ((row & 7) << 4)));
        sacc[n] = __builtin_amdgcn_mfma_f32_16x16x32_bf16(qf[ks], kf, sacc[n], 0, 0, 0);
      }
    }

    // scale + causal mask (diagonal tile only) + wave-parallel online softmax
    float p[4][4];
    float pm[4] = {-3.0e38f, -3.0e38f, -3.0e38f, -3.0e38f};
    const bool diag = (kt == qt);
#pragma unroll
    for (int n = 0; n < 4; ++n)
#pragma unroll
      for (int j = 0; j < 4; ++j){
        float sv = sacc[n][j] * scale;
        if (diag && (n * 16 + lq > wid * 16 + lg * 4 + j)) sv = -3.0e38f;
        p[n][j] = sv;
        pm[j] = fmaxf(pm[j], sv);
      }
#pragma unroll
    for (int j = 0; j < 4; ++j){
#pragma unroll
      for (int m2 = 1; m2 < 16; m2 <<= 1)
        pm[j] = fmaxf(pm[j], __shfl_xor(pm[j], m2, 64));
    }
    float corr[4], rs[4];
#pragma unroll
    for (int j = 0; j < 4; ++j){
      float mnew = fmaxf(mrow[j], pm[j]);
      corr[j] = __builtin_amdgcn_exp2f((mrow[j] - mnew) * LOG2E);
      mrow[j] = mnew;
      rs[j] = 0.f;
    }
#pragma unroll
    for (int n = 0; n < 4; ++n)
#pragma unroll
      for (int j = 0; j < 4; ++j){
        float pv = __builtin_amdgcn_exp2f((p[n][j] - mrow[j]) * LOG2E);
        p[n][j] = pv;
        rs[j] += pv;
      }
#pragma unroll
    for (int j = 0; j < 4; ++j){
#pragma unroll
      for (int m2 = 1; m2 < 16; m2 <<= 1)
        rs[j] += __shfl_xor(rs[j], m2, 64);
      lrow[j] = lrow[j] * corr[j] + rs[j];
    }
#pragma unroll
    for (int n = 0; n < 8; ++n)
#pragma unroll
      for (int j = 0; j < 4; ++j)
        oacc[n][j] *= corr[j];

    // P -> per-wave LDS (bf16), then PV
#pragma unroll
    for (int n = 0; n < 4; ++n)
#pragma unroll
      for (int j = 0; j < 4; ++j)
        Pl[wid][(lg * 4 + j) * 72 + n * 16 + lq] = f2bf(p[n][j]);

#pragma unroll
    for (int ks2 = 0; ks2 < 2; ++ks2){
      bf16x8 pf = *(const bf16x8*)(&Pl[wid][lq * 72 + ks2 * 32 + lg * 8]);
#pragma unroll
      for (int n = 0; n < 8; ++n){
        int d = n * 16 + lq;
        bf16x8 vf = *(const bf16x8*)((const char*)Vt + d * 128 +
                                     ((ks2 * 64 + lg * 16) ^ ((d & 7) << 4)));
        oacc[n] = __builtin_amdgcn_mfma_f32_16x16x32_bf16(pf, vf, oacc[n], 0, 0, 0);
      }
    }
  }

  // epilogue: normalize and write att output [B,S,NH*HD] bf16
#pragma unroll
  for (int j = 0; j < 4; ++j){
    float inv = 1.0f / lrow[j];
    size_t rowoff = ((size_t)b * 2048 + q0 + wid * 16 + lg * 4 + j) * 2048 + (size_t)h * 128;
#pragma unroll
    for (int n = 0; n < 8; ++n)
      O[rowoff + n * 16 + lq] = f2bf(oacc[n][j] * inv);
  }
}

// ---------------- host-side launch ----------------
extern "C" void kernel_launch(void* const* d_in, const int* in_sizes, int n_in,
                              void* d_out, int out_size, void* d_ws, size_t ws_size,
                              hipStream_t stream){
  const float* x  = (const float*)d_in[0];
  const float* wq = (const float*)d_in[1];
  const float* wk = (const float*)d_in[2];
  const float* wv = (const float*)d_in[3];
  const float* wo = (const float*)d_in[4];
  const float* fc = (const float*)d_in[5];
  const float* fs = (const float*)d_in[6];
  float* out = (float*)d_out;
  (void)in_sizes; (void)n_in; (void)out_size; (void)ws_size;

  const size_t XN = (size_t)8192 * 2048;   // B*S*DIM
  const size_t WN = (size_t)2048 * 2048;   // DIM*DIM

  unsigned short* xb  = (unsigned short*)d_ws;
  unsigned short* wqb = xb + XN;
  unsigned short* wkb = wqb + WN;
  unsigned short* wvb = wkb + WN;
  unsigned short* wob = wvb + WN;
  unsigned short* q   = wob + WN;
  unsigned short* k   = q + XN;
  unsigned short* v   = k + XN;
  unsigned short* att = xb;                // alias: x-bf16 dead after QKV GEMMs

  cvt_f32_bf16<<<dim3((unsigned)(XN / 1024)), 256, 0, stream>>>(x, xb);
  cvt_f32_bf16<<<dim3((unsigned)(WN / 1024)), 256, 0, stream>>>(wq, wqb);
  cvt_f32_bf16<<<dim3((unsigned)(WN / 1024)), 256, 0, stream>>>(wk, wkb);
  cvt_f32_bf16<<<dim3((unsigned)(WN / 1024)), 256, 0, stream>>>(wv, wvb);
  cvt_f32_bf16<<<dim3((unsigned)(WN / 1024)), 256, 0, stream>>>(wo, wob);

  dim3 g(16, 64), blk(256);
  gemm_bt<true><<<g, blk, 0, stream>>>(xb, wqb, q, 8192, 2048, 2048);
  gemm_bt<true><<<g, blk, 0, stream>>>(xb, wkb, k, 8192, 2048, 2048);
  gemm_bt<true><<<g, blk, 0, stream>>>(xb, wvb, v, 8192, 2048, 2048);

  rope_kernel<<<dim3(8192), 256, 0, stream>>>(q, k, fc, fs);

  attn_fwd<<<dim3(2048), 256, 0, stream>>>(q, k, v, att);

  gemm_bt<false><<<g, blk, 0, stream>>>(att, wob, out, 8192, 2048, 2048);
}

// Round 2
// 646.510 us; speedup vs baseline: 1.0632x; 1.0632x over previous
//
#include <hip/hip_runtime.h>

typedef __attribute__((ext_vector_type(8))) __bf16 bf16x8;
typedef __attribute__((ext_vector_type(4))) float f32x4;
typedef __attribute__((ext_vector_type(16))) float f32x16;
typedef __attribute__((ext_vector_type(8))) unsigned short u16x8;
typedef __attribute__((ext_vector_type(2))) unsigned uint2v;

#define LOG2E 1.44269504088896340736f

__device__ __forceinline__ unsigned short f2bf(float f){
  union { float f; unsigned u; } v; v.f = f;
  unsigned r = v.u + 0x7FFFu + ((v.u >> 16) & 1u);
  return (unsigned short)(r >> 16);
}
__device__ __forceinline__ float bf2f(unsigned short u){
  union { unsigned u; float f; } v; v.u = ((unsigned)u) << 16;
  return v.f;
}

typedef const unsigned __attribute__((address_space(1)))* gas_ptr;
typedef unsigned __attribute__((address_space(3)))* las_ptr;

__device__ __forceinline__ void gload_lds16(const void* g, void* l){
  __builtin_amdgcn_global_load_lds((gas_ptr)g, (las_ptr)l, 16, 0, 0);
}

__device__ __forceinline__ unsigned cvtpk(float lo, float hi){
  unsigned r;
  asm("v_cvt_pk_bf16_f32 %0, %1, %2" : "=v"(r) : "v"(lo), "v"(hi));
  return r;
}
// (a,b) -> a'={a.lo,b.lo}, b'={a.hi,b.hi}
__device__ __forceinline__ void swap32(unsigned &a, unsigned &b){
  uint2v r = __builtin_amdgcn_permlane32_swap(a, b, false, false);
  a = r[0]; b = r[1];
}

// ---------------- f32 -> bf16 conversion ----------------
__global__ __launch_bounds__(256) void cvt_f32_bf16(const float* __restrict__ in,
                                                    unsigned short* __restrict__ out){
  size_t i = ((size_t)blockIdx.x * 256 + threadIdx.x) * 4;
  float4 vv = *(const float4*)(in + i);
  ushort4 o;
  o.x = f2bf(vv.x); o.y = f2bf(vv.y); o.z = f2bf(vv.z); o.w = f2bf(vv.w);
  *(ushort4*)(out + i) = o;
}

// ---------------- GEMM: C[M,N] = A[M,K] * B[N,K]^T  (m97 structure) ----------------
template<bool OUT_BF16>
__global__ __launch_bounds__(256) void gemm_bt(const unsigned short* __restrict__ A,
                                               const unsigned short* __restrict__ B,
                                               void* __restrict__ Cv,
                                               int M, int N, int K){
  __shared__ unsigned short As[128 * 32];
  __shared__ unsigned short Bs[128 * 32];
  const int tid = threadIdx.x;
  const int l = tid & 63, w = tid >> 6;
  const int lq = l & 15, lg = l >> 4;
  const int wr = w >> 1, wc = w & 1;
  const int br = blockIdx.y, bc = blockIdx.x;

  f32x4 acc[4][4] = {};
  const size_t Abase = (size_t)br * 128 * K;
  const size_t Bbase = (size_t)bc * 128 * K;

  for (int k0 = 0; k0 < K; k0 += 32){
    __syncthreads();
#pragma unroll
    for (int c = 0; c < 2; ++c){
      int off = c * 4096 + w * 1024 + l * 16;
      int row = off >> 6, colb = off & 63;
      gload_lds16((const char*)(A + Abase + (size_t)row * K + k0) + colb,
                  (char*)As + c * 4096 + w * 1024);
      gload_lds16((const char*)(B + Bbase + (size_t)row * K + k0) + colb,
                  (char*)Bs + c * 4096 + w * 1024);
    }
    __syncthreads();

    bf16x8 af[4], bfr[4];
#pragma unroll
    for (int m = 0; m < 4; ++m)
      af[m] = *(const bf16x8*)(As + (wr * 64 + m * 16 + lq) * 32 + lg * 8);
#pragma unroll
    for (int n = 0; n < 4; ++n)
      bfr[n] = *(const bf16x8*)(Bs + (wc * 64 + n * 16 + lq) * 32 + lg * 8);
#pragma unroll
    for (int m = 0; m < 4; ++m)
#pragma unroll
      for (int n = 0; n < 4; ++n)
        acc[m][n] = __builtin_amdgcn_mfma_f32_16x16x32_bf16(af[m], bfr[n], acc[m][n], 0, 0, 0);
  }

  const int r0 = br * 128 + wr * 64 + lg * 4;
  const int c0 = bc * 128 + wc * 64 + lq;
#pragma unroll
  for (int m = 0; m < 4; ++m)
#pragma unroll
    for (int n = 0; n < 4; ++n)
#pragma unroll
      for (int j = 0; j < 4; ++j){
        size_t row = (size_t)(r0 + m * 16 + j);
        int col = c0 + n * 16;
        if (OUT_BF16)
          ((unsigned short*)Cv)[row * N + col] = f2bf(acc[m][n][j]);
        else
          ((float*)Cv)[row * N + col] = acc[m][n][j];
      }
}

// ---------------- RoPE (in-place on bf16 Q and K, layout [B*S][NH*HD]) ----------------
__global__ __launch_bounds__(256) void rope_kernel(unsigned short* __restrict__ q,
                                                   unsigned short* __restrict__ k,
                                                   const float* __restrict__ fc,
                                                   const float* __restrict__ fs){
  int tid = blockIdx.x * 256 + threadIdx.x;
  int col8 = tid & 255;
  int row = tid >> 8;
  int s = row & 2047;
  int i0 = (col8 & 15) * 4;
  size_t eo = (size_t)row * 2048 + (size_t)(col8 >> 4) * 128 + (size_t)(col8 & 15) * 8;
  float4 c = *(const float4*)(fc + (size_t)s * 64 + i0);
  float4 sn = *(const float4*)(fs + (size_t)s * 64 + i0);
  float cs[4] = {c.x, c.y, c.z, c.w};
  float ss[4] = {sn.x, sn.y, sn.z, sn.w};
  u16x8 qv = *(const u16x8*)(q + eo);
  u16x8 kv = *(const u16x8*)(k + eo);
  u16x8 qo, ko;
#pragma unroll
  for (int p2 = 0; p2 < 4; ++p2){
    float a = bf2f(qv[2 * p2]), b = bf2f(qv[2 * p2 + 1]);
    qo[2 * p2]     = f2bf(a * cs[p2] - b * ss[p2]);
    qo[2 * p2 + 1] = f2bf(a * ss[p2] + b * cs[p2]);
    a = bf2f(kv[2 * p2]); b = bf2f(kv[2 * p2 + 1]);
    ko[2 * p2]     = f2bf(a * cs[p2] - b * ss[p2]);
    ko[2 * p2 + 1] = f2bf(a * ss[p2] + b * cs[p2]);
  }
  *(u16x8*)(q + eo) = qo;
  *(u16x8*)(k + eo) = ko;
}

// ---------------- Flash attention (causal), swapped-QK^T 32x32 structure ----------------
// Block: 4 waves x 32 q-rows = 128 q-rows. KV tile = 64.
// S^T = mfma(K,Q): lane owns q = lane&31, 16 kv per reg-half (hi = lane>>5).
// PV: O^T = mfma(Vt, P^T): col = q again -> per-lane scalar softmax state.
__global__ __launch_bounds__(256) void attn_fwd(const unsigned short* __restrict__ Q,
                                                const unsigned short* __restrict__ K,
                                                const unsigned short* __restrict__ V,
                                                unsigned short* __restrict__ O){
  __shared__ unsigned short SMEM[64 * 128 + 128 * 64];   // Ks then Vt (32 KB)
  unsigned short* Ks = SMEM;
  unsigned short* Vt = SMEM + 64 * 128;

  const int tid = threadIdx.x;
  const int l = tid & 63, wid = tid >> 6;
  const int lq = l & 31, hi = l >> 5;
  const int bh = blockIdx.x & 63;
  const int qt = 15 - (blockIdx.x >> 6);      // long blocks first
  const int b = bh >> 4, h = bh & 15;
  const int qw = qt * 128 + wid * 32;         // wave's q base
  const float c2 = 0.12751743f;               // (1/sqrt(128)) * log2(e)

  // Q fragments: B-operand, lane holds q-row (lq), k = hi*8+e per 16-chunk
  const unsigned short* qptr = Q + ((size_t)(b * 2048 + qw + lq)) * 2048 + (size_t)h * 128;
  bf16x8 qf[8];
#pragma unroll
  for (int ks = 0; ks < 8; ++ks)
    qf[ks] = *(const bf16x8*)(qptr + ks * 16 + hi * 8);

  f32x16 oacc[4];
#pragma unroll
  for (int i = 0; i < 4; ++i)
#pragma unroll
    for (int j = 0; j < 16; ++j) oacc[i][j] = 0.f;
  float mrow = -3.0e38f, lrow = 0.f;

  const int nkt = 2 * qt + 2;
  for (int kt = 0; kt < nkt; ++kt){
    __syncthreads();
    const size_t kvbase = ((size_t)(b * 2048 + kt * 64)) * 2048 + (size_t)h * 128;

    // stage K [64][128] via global_load_lds; source pre-swizzled (row&15)<<4
#pragma unroll
    for (int c = 0; c < 4; ++c){
      int off = c * 4096 + wid * 1024 + l * 16;
      int row = off >> 8, colb = off & 255;
      int colbs = colb ^ ((row & 15) << 4);
      gload_lds16((const char*)(K + kvbase + (size_t)row * 2048) + colbs,
                  (char*)Ks + c * 4096 + wid * 1024);
    }
    // stage V transposed: Vt[d][kv], swizzle (d&7)<<4
    {
      const int dblk = tid >> 4, kvp0 = tid & 15;
#pragma unroll
      for (int a2 = 0; a2 < 2; ++a2){
        int kv = 2 * (kvp0 + 16 * a2);
        const unsigned short* vp = V + kvbase + (size_t)kv * 2048 + dblk * 8;
        u16x8 r0 = *(const u16x8*)vp;
        u16x8 r1 = *(const u16x8*)(vp + 2048);
#pragma unroll
        for (int j = 0; j < 8; ++j){
          int d = dblk * 8 + j;
          unsigned val = (unsigned)r0[j] | ((unsigned)r1[j] << 16);
          *(unsigned*)((char*)Vt + d * 128 + ((kv * 2) ^ ((d & 7) << 4))) = val;
        }
      }
    }
    __syncthreads();

    if (kt * 64 > qw + 31) continue;   // fully masked for this wave (uniform)

    // ---- QK^T (swapped): sacc[sub] = S^T[kv 32-block][q] ----
    f32x16 sacc[2];
#pragma unroll
    for (int sub = 0; sub < 2; ++sub){
#pragma unroll
      for (int j = 0; j < 16; ++j) sacc[sub][j] = 0.f;
      const int row = sub * 32 + lq;
      const int swz = (row & 15) << 4;
#pragma unroll
      for (int ks = 0; ks < 8; ++ks){
        bf16x8 kf = *(const bf16x8*)((const char*)Ks + row * 256 + ((ks * 32 + hi * 16) ^ swz));
        sacc[sub] = __builtin_amdgcn_mfma_f32_32x32x16_bf16(kf, qf[ks], sacc[sub], 0, 0, 0);
      }
    }

    float s[32];
#pragma unroll
    for (int sub = 0; sub < 2; ++sub)
#pragma unroll
      for (int r = 0; r < 16; ++r) s[sub * 16 + r] = sacc[sub][r];

    if (kt * 64 + 63 > qw){           // diagonal region: apply causal mask
      const int qg = qw + lq;
#pragma unroll
      for (int sub = 0; sub < 2; ++sub)
#pragma unroll
        for (int r = 0; r < 16; ++r){
          int kvg = kt * 64 + sub * 32 + (r & 3) + 8 * (r >> 2) + 4 * hi;
          if (kvg > qg) s[sub * 16 + r] = -3.0e38f;
        }
    }

    // ---- in-register online softmax (per-lane q-row) ----
    float mx[32];
#pragma unroll
    for (int i = 0; i < 32; ++i) mx[i] = s[i];
#pragma unroll
    for (int st = 1; st < 32; st <<= 1)
#pragma unroll
      for (int i = 0; i < 32; i += 2 * st) mx[i] = fmaxf(mx[i], mx[i + st]);
    float pmax = mx[0];
    pmax = fmaxf(pmax, __shfl_xor(pmax, 32, 64));
    float mnew = fmaxf(mrow, pmax);
    float mm = mnew * c2;
    float corr = __builtin_amdgcn_exp2f(__builtin_fmaf(mrow, c2, -mm));
    mrow = mnew;

    float p[32];
#pragma unroll
    for (int i = 0; i < 32; ++i)
      p[i] = __builtin_amdgcn_exp2f(__builtin_fmaf(s[i], c2, -mm));
    float sm[32];
#pragma unroll
    for (int i = 0; i < 32; ++i) sm[i] = p[i];
#pragma unroll
    for (int st = 1; st < 32; st <<= 1)
#pragma unroll
      for (int i = 0; i < 32; i += 2 * st) sm[i] += sm[i + st];
    float rs = sm[0];
    rs += __shfl_xor(rs, 32, 64);
    lrow = lrow * corr + rs;

#pragma unroll
    for (int i = 0; i < 4; ++i)
#pragma unroll
      for (int j = 0; j < 16; ++j) oacc[i][j] *= corr;

    // ---- P repack: cvt_pk pairs + permlane32_swap -> B-operand fragments ----
    unsigned w[16];
#pragma unroll
    for (int i = 0; i < 16; ++i) w[i] = cvtpk(p[2 * i], p[2 * i + 1]);
    swap32(w[0], w[2]);   swap32(w[1], w[3]);
    swap32(w[4], w[6]);   swap32(w[5], w[7]);
    swap32(w[8], w[10]);  swap32(w[9], w[11]);
    swap32(w[12], w[14]); swap32(w[13], w[15]);

    // ---- PV: oacc[dblk] = O^T[d 32-block][q] ----
#pragma unroll
    for (int c = 0; c < 4; ++c){
      union { unsigned u[4]; bf16x8 v; } pu;
      pu.u[0] = w[c * 4 + 0]; pu.u[1] = w[c * 4 + 1];
      pu.u[2] = w[c * 4 + 2]; pu.u[3] = w[c * 4 + 3];
#pragma unroll
      for (int dblk = 0; dblk < 4; ++dblk){
        const int d = dblk * 32 + lq;
        bf16x8 vf = *(const bf16x8*)((const char*)Vt + d * 128 + ((c * 32 + hi * 16) ^ ((d & 7) << 4)));
        oacc[dblk] = __builtin_amdgcn_mfma_f32_32x32x16_bf16(vf, pu.v, oacc[dblk], 0, 0, 0);
      }
    }
  }

  // ---- epilogue: normalize, transpose O^T -> O via LDS, coalesced store ----
  __syncthreads();
  float inv = 1.0f / lrow;
  char* lb = (char*)SMEM + wid * 8192;   // 32 rows x 256 B per wave
#pragma unroll
  for (int dblk = 0; dblk < 4; ++dblk)
#pragma unroll
    for (int r = 0; r < 16; r += 2){
      int d = dblk * 32 + (r & 3) + 8 * (r >> 2) + 4 * hi;
      unsigned val = (unsigned)f2bf(oacc[dblk][r] * inv) |
                     ((unsigned)f2bf(oacc[dblk][r + 1] * inv) << 16);
      *(unsigned*)(lb + lq * 256 + ((2 * d) ^ ((lq & 7) << 4))) = val;
    }
  __syncthreads();
#pragma unroll
  for (int i = 0; i < 8; ++i){
    int rowq = i * 4 + (l >> 4);
    u16x8 vv = *(const u16x8*)(lb + rowq * 256 + (((l & 15) * 16) ^ ((rowq & 7) << 4)));
    *(u16x8*)(O + ((size_t)(b * 2048 + qw + rowq)) * 2048 + (size_t)h * 128 + (l & 15) * 8) = vv;
  }
}

// ---------------- host-side launch ----------------
extern "C" void kernel_launch(void* const* d_in, const int* in_sizes, int n_in,
                              void* d_out, int out_size, void* d_ws, size_t ws_size,
                              hipStream_t stream){
  const float* x  = (const float*)d_in[0];
  const float* wq = (const float*)d_in[1];
  const float* wk = (const float*)d_in[2];
  const float* wv = (const float*)d_in[3];
  const float* wo = (const float*)d_in[4];
  const float* fc = (const float*)d_in[5];
  const float* fs = (const float*)d_in[6];
  float* out = (float*)d_out;
  (void)in_sizes; (void)n_in; (void)out_size; (void)ws_size;

  const size_t XN = (size_t)8192 * 2048;
  const size_t WN = (size_t)2048 * 2048;

  unsigned short* xb  = (unsigned short*)d_ws;
  unsigned short* wqb = xb + XN;
  unsigned short* wkb = wqb + WN;
  unsigned short* wvb = wkb + WN;
  unsigned short* wob = wvb + WN;
  unsigned short* q   = wob + WN;
  unsigned short* k   = q + XN;
  unsigned short* v   = k + XN;
  unsigned short* att = xb;                // alias: x-bf16 dead after QKV GEMMs

  cvt_f32_bf16<<<dim3((unsigned)(XN / 1024)), 256, 0, stream>>>(x, xb);
  cvt_f32_bf16<<<dim3((unsigned)(WN / 1024)), 256, 0, stream>>>(wq, wqb);
  cvt_f32_bf16<<<dim3((unsigned)(WN / 1024)), 256, 0, stream>>>(wk, wkb);
  cvt_f32_bf16<<<dim3((unsigned)(WN / 1024)), 256, 0, stream>>>(wv, wvb);
  cvt_f32_bf16<<<dim3((unsigned)(WN / 1024)), 256, 0, stream>>>(wo, wob);

  dim3 g(16, 64), blk(256);
  gemm_bt<true><<<g, blk, 0, stream>>>(xb, wqb, q, 8192, 2048, 2048);
  gemm_bt<true><<<g, blk, 0, stream>>>(xb, wkb, k, 8192, 2048, 2048);
  gemm_bt<true><<<g, blk, 0, stream>>>(xb, wvb, v, 8192, 2048, 2048);

  rope_kernel<<<dim3(8192), 256, 0, stream>>>(q, k, fc, fs);

  attn_fwd<<<dim3(1024), 256, 0, stream>>>(q, k, v, att);

  gemm_bt<false><<<g, blk, 0, stream>>>(att, wob, out, 8192, 2048, 2048);
}

// Round 3
// 506.884 us; speedup vs baseline: 1.3560x; 1.2755x over previous
//
#include <hip/hip_runtime.h>

typedef __attribute__((ext_vector_type(8))) __bf16 bf16x8;
typedef __attribute__((ext_vector_type(4))) float f32x4;
typedef __attribute__((ext_vector_type(16))) float f32x16;
typedef __attribute__((ext_vector_type(8))) unsigned short u16x8;
typedef __attribute__((ext_vector_type(2))) unsigned uint2v;

#define LOG2E 1.44269504088896340736f

__device__ __forceinline__ unsigned short f2bf(float f){
  union { float f; unsigned u; } v; v.f = f;
  unsigned r = v.u + 0x7FFFu + ((v.u >> 16) & 1u);
  return (unsigned short)(r >> 16);
}
__device__ __forceinline__ float bf2f(unsigned short u){
  union { unsigned u; float f; } v; v.u = ((unsigned)u) << 16;
  return v.f;
}

typedef const unsigned __attribute__((address_space(1)))* gas_ptr;
typedef unsigned __attribute__((address_space(3)))* las_ptr;

__device__ __forceinline__ void gload_lds16(const void* g, void* l){
  __builtin_amdgcn_global_load_lds((gas_ptr)g, (las_ptr)l, 16, 0, 0);
}

__device__ __forceinline__ unsigned cvtpk(float lo, float hi){
  unsigned r;
  asm("v_cvt_pk_bf16_f32 %0, %1, %2" : "=v"(r) : "v"(lo), "v"(hi));
  return r;
}
__device__ __forceinline__ void swap32(unsigned &a, unsigned &b){
  uint2v r = __builtin_amdgcn_permlane32_swap(a, b, false, false);
  a = r[0]; b = r[1];
}

// ---------------- f32 -> bf16 conversion ----------------
__global__ __launch_bounds__(256) void cvt_f32_bf16(const float* __restrict__ in,
                                                    unsigned short* __restrict__ out){
  size_t i = ((size_t)blockIdx.x * 256 + threadIdx.x) * 4;
  float4 vv = *(const float4*)(in + i);
  ushort4 o;
  o.x = f2bf(vv.x); o.y = f2bf(vv.y); o.z = f2bf(vv.z); o.w = f2bf(vv.w);
  *(ushort4*)(out + i) = o;
}

// ============ 256x256 8-phase GEMM: C[M,N] = A[M,K] * B[N,K]^T ============
// 8 waves (2x4), BK=64, 2 K-tiles per iteration pattern collapsed to 4 phases
// per K-tile; counted vmcnt(4) at tile boundaries (2 half-tiles in flight).
// LDS: 8 half-buffers x 16KB = 128KB, (op, half, parity).
// Swizzle: 16B-chunk index ^= (row & 7), pre-swizzled global source (rule #21).

#define BUF(op, half, par) (LDS + (((op) * 2 + (half)) * 2 + (par)) * 16384)

#define STAGE(op, gbase, half, par, kt) do {                                   \
  _Pragma("unroll")                                                            \
  for (int c_ = 0; c_ < 2; ++c_){                                              \
    int slot_ = c_ * 512 + w * 64 + l;                                         \
    int row_ = slot_ >> 3, colb_ = slot_ & 7;                                  \
    gload_lds16((const char*)((gbase) + (size_t)((half) * 128 + row_) * K +    \
                              (size_t)(kt) * 64 + ((colb_ ^ (row_ & 7)) * 8)), \
                BUF(op, half, par) + c_ * 8192 + w * 1024);                    \
  } } while (0)

#define PHASE(mh, nh, par, ...) do {                                           \
  bf16x8 af_[4][2], bf_[2][2];                                                 \
  const char* Ab_ = BUF(0, mh, par);                                           \
  const char* Bb_ = BUF(1, nh, par);                                           \
  _Pragma("unroll")                                                            \
  for (int i_ = 0; i_ < 4; ++i_){                                              \
    int row_ = wm * 64 + i_ * 16 + lq;                                         \
    _Pragma("unroll")                                                          \
    for (int ks_ = 0; ks_ < 2; ++ks_)                                          \
      af_[i_][ks_] = *(const bf16x8*)(Ab_ + row_ * 128 +                       \
                                      (((ks_ * 4 + lg) ^ (row_ & 7)) * 16));   \
  }                                                                            \
  _Pragma("unroll")                                                            \
  for (int j_ = 0; j_ < 2; ++j_){                                              \
    int row_ = wn * 32 + j_ * 16 + lq;                                         \
    _Pragma("unroll")                                                          \
    for (int ks_ = 0; ks_ < 2; ++ks_)                                          \
      bf_[j_][ks_] = *(const bf16x8*)(Bb_ + row_ * 128 +                       \
                                      (((ks_ * 4 + lg) ^ (row_ & 7)) * 16));   \
  }                                                                            \
  __VA_ARGS__;                                                                 \
  __builtin_amdgcn_s_barrier();                                                \
  asm volatile("s_waitcnt lgkmcnt(0)");                                        \
  __builtin_amdgcn_s_setprio(1);                                               \
  _Pragma("unroll")                                                            \
  for (int i_ = 0; i_ < 4; ++i_)                                               \
    _Pragma("unroll")                                                          \
    for (int j_ = 0; j_ < 2; ++j_)                                             \
      _Pragma("unroll")                                                        \
      for (int ks_ = 0; ks_ < 2; ++ks_)                                        \
        acc[(mh) * 4 + i_][(nh) * 2 + j_] = __builtin_amdgcn_mfma_f32_16x16x32_bf16( \
            af_[i_][ks_], bf_[j_][ks_], acc[(mh) * 4 + i_][(nh) * 2 + j_], 0, 0, 0); \
  __builtin_amdgcn_s_setprio(0);                                               \
  __builtin_amdgcn_s_barrier();                                                \
} while (0)

template<bool OUT_BF16>
__global__ __launch_bounds__(512, 2) void gemm256(const unsigned short* __restrict__ A,
                                                  const unsigned short* __restrict__ B,
                                                  void* __restrict__ Cv,
                                                  int M, int N, int K){
  __shared__ char LDS[131072];
  const int tid = threadIdx.x;
  const int l = tid & 63, w = tid >> 6;
  const int lq = l & 15, lg = l >> 4;
  const int wm = w >> 2, wn = w & 3;

  // XCD-aware bijective swizzle (grid multiple of 8)
  const int nwg = gridDim.x, cpx = nwg >> 3;
  const int orig = blockIdx.x;
  const int sw = (orig & 7) * cpx + (orig >> 3);
  const int nbc = N >> 8;
  const int br = sw / nbc, bc = sw % nbc;

  f32x4 acc[8][4] = {};
  const unsigned short* Ag = A + (size_t)br * 256 * K;
  const unsigned short* Bg = B + (size_t)bc * 256 * K;
  const int NT = K >> 6;

  // prologue: tile0 all 4 halves (par 0); tile1 B0,A0 (par 1) left in flight
  STAGE(0, Ag, 0, 0, 0); STAGE(1, Bg, 0, 0, 0);
  STAGE(0, Ag, 1, 0, 0); STAGE(1, Bg, 1, 0, 0);
  STAGE(1, Bg, 0, 1, 1); STAGE(0, Ag, 0, 1, 1);
  asm volatile("s_waitcnt vmcnt(4)" ::: "memory");
  __builtin_amdgcn_s_barrier();

  for (int t = 0; t < NT; ++t){
    const int par = t & 1, parn = par ^ 1;
    PHASE(0, 0, par, { if (t + 1 < NT) STAGE(0, Ag, 1, parn, t + 1); });
    PHASE(1, 0, par, { if (t + 1 < NT) STAGE(1, Bg, 1, parn, t + 1); });
    PHASE(0, 1, par, { if (t + 2 < NT) STAGE(1, Bg, 0, par, t + 2); });
    PHASE(1, 1, par, { if (t + 2 < NT) STAGE(0, Ag, 0, par, t + 2); });
    asm volatile("s_waitcnt vmcnt(4)" ::: "memory");
    __builtin_amdgcn_s_barrier();
  }

  // epilogue: C write (row = A-side lg*4+r, col = B-side lq; verified layout)
#pragma unroll
  for (int i = 0; i < 8; ++i){
    int grow = br * 256 + (i >> 2) * 128 + wm * 64 + (i & 3) * 16 + lg * 4;
#pragma unroll
    for (int j = 0; j < 4; ++j){
      int gcol = bc * 256 + (j >> 1) * 128 + wn * 32 + (j & 1) * 16 + lq;
#pragma unroll
      for (int r = 0; r < 4; ++r){
        if (OUT_BF16)
          ((unsigned short*)Cv)[(size_t)(grow + r) * N + gcol] = f2bf(acc[i][j][r]);
        else
          ((float*)Cv)[(size_t)(grow + r) * N + gcol] = acc[i][j][r];
      }
    }
  }
}

// ---------------- RoPE (in-place on bf16 Q and K, layout [B*S][NH*HD]) ----------------
__global__ __launch_bounds__(256) void rope_kernel(unsigned short* __restrict__ q,
                                                   unsigned short* __restrict__ k,
                                                   const float* __restrict__ fc,
                                                   const float* __restrict__ fs){
  int tid = blockIdx.x * 256 + threadIdx.x;
  int col8 = tid & 255;
  int row = tid >> 8;
  int s = row & 2047;
  int i0 = (col8 & 15) * 4;
  size_t eo = (size_t)row * 2048 + (size_t)(col8 >> 4) * 128 + (size_t)(col8 & 15) * 8;
  float4 c = *(const float4*)(fc + (size_t)s * 64 + i0);
  float4 sn = *(const float4*)(fs + (size_t)s * 64 + i0);
  float cs[4] = {c.x, c.y, c.z, c.w};
  float ss[4] = {sn.x, sn.y, sn.z, sn.w};
  u16x8 qv = *(const u16x8*)(q + eo);
  u16x8 kv = *(const u16x8*)(k + eo);
  u16x8 qo, ko;
#pragma unroll
  for (int p2 = 0; p2 < 4; ++p2){
    float a = bf2f(qv[2 * p2]), b = bf2f(qv[2 * p2 + 1]);
    qo[2 * p2]     = f2bf(a * cs[p2] - b * ss[p2]);
    qo[2 * p2 + 1] = f2bf(a * ss[p2] + b * cs[p2]);
    a = bf2f(kv[2 * p2]); b = bf2f(kv[2 * p2 + 1]);
    ko[2 * p2]     = f2bf(a * cs[p2] - b * ss[p2]);
    ko[2 * p2 + 1] = f2bf(a * ss[p2] + b * cs[p2]);
  }
  *(u16x8*)(q + eo) = qo;
  *(u16x8*)(k + eo) = ko;
}

// ---------------- Flash attention (causal), swapped-QK^T 32x32 structure ----------------
__global__ __launch_bounds__(256) void attn_fwd(const unsigned short* __restrict__ Q,
                                                const unsigned short* __restrict__ K,
                                                const unsigned short* __restrict__ V,
                                                unsigned short* __restrict__ O){
  __shared__ unsigned short SMEM[64 * 128 + 128 * 64];
  unsigned short* Ks = SMEM;
  unsigned short* Vt = SMEM + 64 * 128;

  const int tid = threadIdx.x;
  const int l = tid & 63, wid = tid >> 6;
  const int lq = l & 31, hi = l >> 5;
  const int bh = blockIdx.x & 63;
  const int qt = 15 - (blockIdx.x >> 6);
  const int b = bh >> 4, h = bh & 15;
  const int qw = qt * 128 + wid * 32;
  const float c2 = 0.12751743f;   // (1/sqrt(128)) * log2(e)

  const unsigned short* qptr = Q + ((size_t)(b * 2048 + qw + lq)) * 2048 + (size_t)h * 128;
  bf16x8 qf[8];
#pragma unroll
  for (int ks = 0; ks < 8; ++ks)
    qf[ks] = *(const bf16x8*)(qptr + ks * 16 + hi * 8);

  f32x16 oacc[4];
#pragma unroll
  for (int i = 0; i < 4; ++i)
#pragma unroll
    for (int j = 0; j < 16; ++j) oacc[i][j] = 0.f;
  float mrow = -3.0e38f, lrow = 0.f;

  const int nkt = 2 * qt + 2;
  for (int kt = 0; kt < nkt; ++kt){
    __syncthreads();
    const size_t kvbase = ((size_t)(b * 2048 + kt * 64)) * 2048 + (size_t)h * 128;

#pragma unroll
    for (int c = 0; c < 4; ++c){
      int off = c * 4096 + wid * 1024 + l * 16;
      int row = off >> 8, colb = off & 255;
      int colbs = colb ^ ((row & 15) << 4);
      gload_lds16((const char*)(K + kvbase + (size_t)row * 2048) + colbs,
                  (char*)Ks + c * 4096 + wid * 1024);
    }
    {
      const int dblk = tid >> 4, kvp0 = tid & 15;
#pragma unroll
      for (int a2 = 0; a2 < 2; ++a2){
        int kv = 2 * (kvp0 + 16 * a2);
        const unsigned short* vp = V + kvbase + (size_t)kv * 2048 + dblk * 8;
        u16x8 r0 = *(const u16x8*)vp;
        u16x8 r1 = *(const u16x8*)(vp + 2048);
#pragma unroll
        for (int j = 0; j < 8; ++j){
          int d = dblk * 8 + j;
          unsigned val = (unsigned)r0[j] | ((unsigned)r1[j] << 16);
          *(unsigned*)((char*)Vt + d * 128 + ((kv * 2) ^ ((d & 7) << 4))) = val;
        }
      }
    }
    __syncthreads();

    if (kt * 64 > qw + 31) continue;

    f32x16 sacc[2];
#pragma unroll
    for (int sub = 0; sub < 2; ++sub){
#pragma unroll
      for (int j = 0; j < 16; ++j) sacc[sub][j] = 0.f;
      const int row = sub * 32 + lq;
      const int swz = (row & 15) << 4;
#pragma unroll
      for (int ks = 0; ks < 8; ++ks){
        bf16x8 kf = *(const bf16x8*)((const char*)Ks + row * 256 + ((ks * 32 + hi * 16) ^ swz));
        sacc[sub] = __builtin_amdgcn_mfma_f32_32x32x16_bf16(kf, qf[ks], sacc[sub], 0, 0, 0);
      }
    }

    float s[32];
#pragma unroll
    for (int sub = 0; sub < 2; ++sub)
#pragma unroll
      for (int r = 0; r < 16; ++r) s[sub * 16 + r] = sacc[sub][r];

    if (kt * 64 + 63 > qw){
      const int qg = qw + lq;
#pragma unroll
      for (int sub = 0; sub < 2; ++sub)
#pragma unroll
        for (int r = 0; r < 16; ++r){
          int kvg = kt * 64 + sub * 32 + (r & 3) + 8 * (r >> 2) + 4 * hi;
          if (kvg > qg) s[sub * 16 + r] = -3.0e38f;
        }
    }

    float mx[32];
#pragma unroll
    for (int i = 0; i < 32; ++i) mx[i] = s[i];
#pragma unroll
    for (int st = 1; st < 32; st <<= 1)
#pragma unroll
      for (int i = 0; i < 32; i += 2 * st) mx[i] = fmaxf(mx[i], mx[i + st]);
    float pmax = mx[0];
    pmax = fmaxf(pmax, __shfl_xor(pmax, 32, 64));
    float mnew = fmaxf(mrow, pmax);
    float mm = mnew * c2;
    float corr = __builtin_amdgcn_exp2f(__builtin_fmaf(mrow, c2, -mm));
    mrow = mnew;

    float p[32];
#pragma unroll
    for (int i = 0; i < 32; ++i)
      p[i] = __builtin_amdgcn_exp2f(__builtin_fmaf(s[i], c2, -mm));
    float sm[32];
#pragma unroll
    for (int i = 0; i < 32; ++i) sm[i] = p[i];
#pragma unroll
    for (int st = 1; st < 32; st <<= 1)
#pragma unroll
      for (int i = 0; i < 32; i += 2 * st) sm[i] += sm[i + st];
    float rs = sm[0];
    rs += __shfl_xor(rs, 32, 64);
    lrow = lrow * corr + rs;

#pragma unroll
    for (int i = 0; i < 4; ++i)
#pragma unroll
      for (int j = 0; j < 16; ++j) oacc[i][j] *= corr;

    unsigned wv[16];
#pragma unroll
    for (int i = 0; i < 16; ++i) wv[i] = cvtpk(p[2 * i], p[2 * i + 1]);
    swap32(wv[0], wv[2]);   swap32(wv[1], wv[3]);
    swap32(wv[4], wv[6]);   swap32(wv[5], wv[7]);
    swap32(wv[8], wv[10]);  swap32(wv[9], wv[11]);
    swap32(wv[12], wv[14]); swap32(wv[13], wv[15]);

#pragma unroll
    for (int c = 0; c < 4; ++c){
      union { unsigned u[4]; bf16x8 v; } pu;
      pu.u[0] = wv[c * 4 + 0]; pu.u[1] = wv[c * 4 + 1];
      pu.u[2] = wv[c * 4 + 2]; pu.u[3] = wv[c * 4 + 3];
#pragma unroll
      for (int dblk = 0; dblk < 4; ++dblk){
        const int d = dblk * 32 + lq;
        bf16x8 vf = *(const bf16x8*)((const char*)Vt + d * 128 + ((c * 32 + hi * 16) ^ ((d & 7) << 4)));
        oacc[dblk] = __builtin_amdgcn_mfma_f32_32x32x16_bf16(vf, pu.v, oacc[dblk], 0, 0, 0);
      }
    }
  }

  __syncthreads();
  float inv = 1.0f / lrow;
  char* lb = (char*)SMEM + wid * 8192;
#pragma unroll
  for (int dblk = 0; dblk < 4; ++dblk)
#pragma unroll
    for (int r = 0; r < 16; r += 2){
      int d = dblk * 32 + (r & 3) + 8 * (r >> 2) + 4 * hi;
      unsigned val = (unsigned)f2bf(oacc[dblk][r] * inv) |
                     ((unsigned)f2bf(oacc[dblk][r + 1] * inv) << 16);
      *(unsigned*)(lb + lq * 256 + ((2 * d) ^ ((lq & 7) << 4)));
      *(unsigned*)(lb + lq * 256 + ((2 * d) ^ ((lq & 7) << 4))) = val;
    }
  __syncthreads();
#pragma unroll
  for (int i = 0; i < 8; ++i){
    int rowq = i * 4 + (l >> 4);
    u16x8 vv = *(const u16x8*)(lb + rowq * 256 + (((l & 15) * 16) ^ ((rowq & 7) << 4)));
    *(u16x8*)(O + ((size_t)(b * 2048 + qw + rowq)) * 2048 + (size_t)h * 128 + (l & 15) * 8) = vv;
  }
}

// ---------------- host-side launch ----------------
extern "C" void kernel_launch(void* const* d_in, const int* in_sizes, int n_in,
                              void* d_out, int out_size, void* d_ws, size_t ws_size,
                              hipStream_t stream){
  const float* x  = (const float*)d_in[0];
  const float* wq = (const float*)d_in[1];
  const float* wk = (const float*)d_in[2];
  const float* wv = (const float*)d_in[3];
  const float* wo = (const float*)d_in[4];
  const float* fc = (const float*)d_in[5];
  const float* fs = (const float*)d_in[6];
  float* out = (float*)d_out;
  (void)in_sizes; (void)n_in; (void)out_size; (void)ws_size;

  const size_t XN = (size_t)8192 * 2048;
  const size_t WN = (size_t)2048 * 2048;

  unsigned short* xb  = (unsigned short*)d_ws;
  unsigned short* wqb = xb + XN;
  unsigned short* wkb = wqb + WN;
  unsigned short* wvb = wkb + WN;
  unsigned short* wob = wvb + WN;
  unsigned short* q   = wob + WN;
  unsigned short* k   = q + XN;
  unsigned short* v   = k + XN;
  unsigned short* att = xb;                // alias: x-bf16 dead after QKV GEMMs

  cvt_f32_bf16<<<dim3((unsigned)(XN / 1024)), 256, 0, stream>>>(x, xb);
  cvt_f32_bf16<<<dim3((unsigned)(WN / 1024)), 256, 0, stream>>>(wq, wqb);
  cvt_f32_bf16<<<dim3((unsigned)(WN / 1024)), 256, 0, stream>>>(wk, wkb);
  cvt_f32_bf16<<<dim3((unsigned)(WN / 1024)), 256, 0, stream>>>(wv, wvb);
  cvt_f32_bf16<<<dim3((unsigned)(WN / 1024)), 256, 0, stream>>>(wo, wob);

  gemm256<true><<<dim3(256), 512, 0, stream>>>(xb, wqb, q, 8192, 2048, 2048);
  gemm256<true><<<dim3(256), 512, 0, stream>>>(xb, wkb, k, 8192, 2048, 2048);
  gemm256<true><<<dim3(256), 512, 0, stream>>>(xb, wvb, v, 8192, 2048, 2048);

  rope_kernel<<<dim3(8192), 256, 0, stream>>>(q, k, fc, fs);

  attn_fwd<<<dim3(1024), 256, 0, stream>>>(q, k, v, att);

  gemm256<false><<<dim3(256), 512, 0, stream>>>(att, wob, out, 8192, 2048, 2048);
}

// Round 4
// 449.245 us; speedup vs baseline: 1.5300x; 1.1283x over previous
//
#include <hip/hip_runtime.h>

typedef __attribute__((ext_vector_type(8))) __bf16 bf16x8;
typedef __attribute__((ext_vector_type(4))) float f32x4;
typedef __attribute__((ext_vector_type(16))) float f32x16;
typedef __attribute__((ext_vector_type(8))) unsigned short u16x8;
typedef __attribute__((ext_vector_type(2))) unsigned uint2v;

#define LOG2E 1.44269504088896340736f

__device__ __forceinline__ unsigned short f2bf(float f){
  union { float f; unsigned u; } v; v.f = f;
  unsigned r = v.u + 0x7FFFu + ((v.u >> 16) & 1u);
  return (unsigned short)(r >> 16);
}
__device__ __forceinline__ float bf2f(unsigned short u){
  union { unsigned u; float f; } v; v.u = ((unsigned)u) << 16;
  return v.f;
}

typedef const unsigned __attribute__((address_space(1)))* gas_ptr;
typedef unsigned __attribute__((address_space(3)))* las_ptr;

__device__ __forceinline__ void gload_lds16(const void* g, void* l){
  __builtin_amdgcn_global_load_lds((gas_ptr)g, (las_ptr)l, 16, 0, 0);
}

__device__ __forceinline__ unsigned cvtpk(float lo, float hi){
  unsigned r;
  asm("v_cvt_pk_bf16_f32 %0, %1, %2" : "=v"(r) : "v"(lo), "v"(hi));
  return r;
}
__device__ __forceinline__ void swap32(unsigned &a, unsigned &b){
  uint2v r = __builtin_amdgcn_permlane32_swap(a, b, false, false);
  a = r[0]; b = r[1];
}

// ---------------- f32 -> bf16 conversion ----------------
__global__ __launch_bounds__(256) void cvt_f32_bf16(const float* __restrict__ in,
                                                    unsigned short* __restrict__ out){
  size_t i = ((size_t)blockIdx.x * 256 + threadIdx.x) * 4;
  float4 vv = *(const float4*)(in + i);
  ushort4 o;
  o.x = f2bf(vv.x); o.y = f2bf(vv.y); o.z = f2bf(vv.z); o.w = f2bf(vv.w);
  *(ushort4*)(out + i) = o;
}

// ============ 256x256 8-phase GEMM: C[M,N] = A[M,K] * B[N,K]^T ============
#define BUF(op, half, par) (LDS + (((op) * 2 + (half)) * 2 + (par)) * 16384)

#define STAGE(op, gbase, half, par, kt) do {                                   \
  _Pragma("unroll")                                                            \
  for (int c_ = 0; c_ < 2; ++c_){                                              \
    int slot_ = c_ * 512 + w * 64 + l;                                         \
    int row_ = slot_ >> 3, colb_ = slot_ & 7;                                  \
    gload_lds16((const char*)((gbase) + (size_t)((half) * 128 + row_) * K +    \
                              (size_t)(kt) * 64 + ((colb_ ^ (row_ & 7)) * 8)), \
                BUF(op, half, par) + c_ * 8192 + w * 1024);                    \
  } } while (0)

#define PHASE(mh, nh, par, ...) do {                                           \
  bf16x8 af_[4][2], bf_[2][2];                                                 \
  const char* Ab_ = BUF(0, mh, par);                                           \
  const char* Bb_ = BUF(1, nh, par);                                           \
  _Pragma("unroll")                                                            \
  for (int i_ = 0; i_ < 4; ++i_){                                              \
    int row_ = wm * 64 + i_ * 16 + lq;                                         \
    _Pragma("unroll")                                                          \
    for (int ks_ = 0; ks_ < 2; ++ks_)                                          \
      af_[i_][ks_] = *(const bf16x8*)(Ab_ + row_ * 128 +                       \
                                      (((ks_ * 4 + lg) ^ (row_ & 7)) * 16));   \
  }                                                                            \
  _Pragma("unroll")                                                            \
  for (int j_ = 0; j_ < 2; ++j_){                                              \
    int row_ = wn * 32 + j_ * 16 + lq;                                         \
    _Pragma("unroll")                                                          \
    for (int ks_ = 0; ks_ < 2; ++ks_)                                          \
      bf_[j_][ks_] = *(const bf16x8*)(Bb_ + row_ * 128 +                       \
                                      (((ks_ * 4 + lg) ^ (row_ & 7)) * 16));   \
  }                                                                            \
  __VA_ARGS__;                                                                 \
  __builtin_amdgcn_s_barrier();                                                \
  asm volatile("s_waitcnt lgkmcnt(0)");                                        \
  __builtin_amdgcn_s_setprio(1);                                               \
  _Pragma("unroll")                                                            \
  for (int i_ = 0; i_ < 4; ++i_)                                               \
    _Pragma("unroll")                                                          \
    for (int j_ = 0; j_ < 2; ++j_)                                             \
      _Pragma("unroll")                                                        \
      for (int ks_ = 0; ks_ < 2; ++ks_)                                        \
        acc[(mh) * 4 + i_][(nh) * 2 + j_] = __builtin_amdgcn_mfma_f32_16x16x32_bf16( \
            af_[i_][ks_], bf_[j_][ks_], acc[(mh) * 4 + i_][(nh) * 2 + j_], 0, 0, 0); \
  __builtin_amdgcn_s_setprio(0);                                               \
  __builtin_amdgcn_s_barrier();                                                \
} while (0)

template<bool OUT_BF16>
__global__ __launch_bounds__(512, 2) void gemm256(const unsigned short* __restrict__ A,
                                                  const unsigned short* __restrict__ B,
                                                  void* __restrict__ Cv,
                                                  int M, int N, int K){
  __shared__ char LDS[131072];
  const int tid = threadIdx.x;
  const int l = tid & 63, w = tid >> 6;
  const int lq = l & 15, lg = l >> 4;
  const int wm = w >> 2, wn = w & 3;

  const int nwg = gridDim.x, cpx = nwg >> 3;
  const int orig = blockIdx.x;
  const int sw = (orig & 7) * cpx + (orig >> 3);
  const int nbc = N >> 8;
  const int br = sw / nbc, bc = sw % nbc;

  f32x4 acc[8][4] = {};
  const unsigned short* Ag = A + (size_t)br * 256 * K;
  const unsigned short* Bg = B + (size_t)bc * 256 * K;
  const int NT = K >> 6;

  STAGE(0, Ag, 0, 0, 0); STAGE(1, Bg, 0, 0, 0);
  STAGE(0, Ag, 1, 0, 0); STAGE(1, Bg, 1, 0, 0);
  STAGE(1, Bg, 0, 1, 1); STAGE(0, Ag, 0, 1, 1);
  asm volatile("s_waitcnt vmcnt(4)" ::: "memory");
  __builtin_amdgcn_s_barrier();

  for (int t = 0; t < NT; ++t){
    const int par = t & 1, parn = par ^ 1;
    PHASE(0, 0, par, { if (t + 1 < NT) STAGE(0, Ag, 1, parn, t + 1); });
    PHASE(1, 0, par, { if (t + 1 < NT) STAGE(1, Bg, 1, parn, t + 1); });
    PHASE(0, 1, par, { if (t + 2 < NT) STAGE(1, Bg, 0, par, t + 2); });
    PHASE(1, 1, par, { if (t + 2 < NT) STAGE(0, Ag, 0, par, t + 2); });
    asm volatile("s_waitcnt vmcnt(4)" ::: "memory");
    __builtin_amdgcn_s_barrier();
  }

#pragma unroll
  for (int i = 0; i < 8; ++i){
    int grow = br * 256 + (i >> 2) * 128 + wm * 64 + (i & 3) * 16 + lg * 4;
#pragma unroll
    for (int j = 0; j < 4; ++j){
      int gcol = bc * 256 + (j >> 1) * 128 + wn * 32 + (j & 1) * 16 + lq;
#pragma unroll
      for (int r = 0; r < 4; ++r){
        if (OUT_BF16)
          ((unsigned short*)Cv)[(size_t)(grow + r) * N + gcol] = f2bf(acc[i][j][r]);
        else
          ((float*)Cv)[(size_t)(grow + r) * N + gcol] = acc[i][j][r];
      }
    }
  }
}

// ---------------- RoPE (in-place on bf16 Q and K, layout [B*S][NH*HD]) ----------------
__global__ __launch_bounds__(256) void rope_kernel(unsigned short* __restrict__ q,
                                                   unsigned short* __restrict__ k,
                                                   const float* __restrict__ fc,
                                                   const float* __restrict__ fs){
  int tid = blockIdx.x * 256 + threadIdx.x;
  int col8 = tid & 255;
  int row = tid >> 8;
  int s = row & 2047;
  int i0 = (col8 & 15) * 4;
  size_t eo = (size_t)row * 2048 + (size_t)(col8 >> 4) * 128 + (size_t)(col8 & 15) * 8;
  float4 c = *(const float4*)(fc + (size_t)s * 64 + i0);
  float4 sn = *(const float4*)(fs + (size_t)s * 64 + i0);
  float cs[4] = {c.x, c.y, c.z, c.w};
  float ss[4] = {sn.x, sn.y, sn.z, sn.w};
  u16x8 qv = *(const u16x8*)(q + eo);
  u16x8 kv = *(const u16x8*)(k + eo);
  u16x8 qo, ko;
#pragma unroll
  for (int p2 = 0; p2 < 4; ++p2){
    float a = bf2f(qv[2 * p2]), b = bf2f(qv[2 * p2 + 1]);
    qo[2 * p2]     = f2bf(a * cs[p2] - b * ss[p2]);
    qo[2 * p2 + 1] = f2bf(a * ss[p2] + b * cs[p2]);
    a = bf2f(kv[2 * p2]); b = bf2f(kv[2 * p2 + 1]);
    ko[2 * p2]     = f2bf(a * cs[p2] - b * ss[p2]);
    ko[2 * p2 + 1] = f2bf(a * ss[p2] + b * cs[p2]);
  }
  *(u16x8*)(q + eo) = qo;
  *(u16x8*)(k + eo) = ko;
}

// ---------------- Flash attention (causal), swapped-QK^T, 8 waves, dbuf ----------------
// 512 threads = 8 waves x 32 q-rows = 256 q-rows/block. KV tile 64, double-buffered.
// Prefetch: K(t+1) via global_load_lds, V(t+1) via regs; vmcnt(0)+pack after compute;
// ONE barrier per tile (race-free: writes target buffer last read before prev barrier).
__global__ __launch_bounds__(512, 2) void attn_fwd(const unsigned short* __restrict__ Q,
                                                   const unsigned short* __restrict__ K,
                                                   const unsigned short* __restrict__ V,
                                                   unsigned short* __restrict__ O){
  __shared__ unsigned short SMEM[2 * 64 * 128 + 2 * 128 * 64];   // 64 KB
  unsigned short* Ks = SMEM;            // + buf*8192 elems
  unsigned short* Vt = SMEM + 16384;    // + buf*8192 elems

  const int tid = threadIdx.x;
  const int l = tid & 63, wid = tid >> 6;
  const int lq = l & 31, hi = l >> 5;
  const int bh = blockIdx.x & 63;
  const int qt = 7 - (blockIdx.x >> 6);       // long blocks first
  const int b = bh >> 4, h = bh & 15;
  const int qw = qt * 256 + wid * 32;
  const float c2 = 0.12751743f;               // (1/sqrt(128)) * log2(e)

  const unsigned short* qptr = Q + ((size_t)(b * 2048 + qw + lq)) * 2048 + (size_t)h * 128;
  bf16x8 qf[8];
#pragma unroll
  for (int ks = 0; ks < 8; ++ks)
    qf[ks] = *(const bf16x8*)(qptr + ks * 16 + hi * 8);

  f32x16 oacc[4];
#pragma unroll
  for (int i = 0; i < 4; ++i)
#pragma unroll
    for (int j = 0; j < 16; ++j) oacc[i][j] = 0.f;
  float mrow = -3.0e38f, lrow = 0.f;

  const int dblk = tid >> 5, kvp = tid & 31;  // V staging coords
  const size_t hb = (size_t)b * 2048 * 2048 + (size_t)h * 128;
  u16x8 r0, r1;

  // ---- prologue: stage tile 0 into buf 0 ----
  {
    const size_t kvb = hb;
#pragma unroll
    for (int c = 0; c < 2; ++c){
      int off = c * 8192 + tid * 16;
      int row = off >> 8, colb = off & 255;
      gload_lds16((const char*)(K + kvb + (size_t)row * 2048) + (colb ^ ((row & 15) << 4)),
                  (char*)Ks + c * 8192 + (tid >> 6) * 1024 + (tid & 63) * 16);
    }
    const unsigned short* vp = V + kvb + (size_t)(2 * kvp) * 2048 + dblk * 8;
    r0 = *(const u16x8*)vp; r1 = *(const u16x8*)(vp + 2048);
    asm volatile("s_waitcnt vmcnt(0)" ::: "memory");
#pragma unroll
    for (int j = 0; j < 8; ++j){
      int d = dblk * 8 + j;
      unsigned val = (unsigned)r0[j] | ((unsigned)r1[j] << 16);
      *(unsigned*)((char*)Vt + d * 128 + ((4 * kvp) ^ ((d & 7) << 4))) = val;
    }
  }
  __syncthreads();

  const int nkt = 4 * qt + 4;
  for (int kt = 0; kt < nkt; ++kt){
    const int cur = kt & 1, nxt = cur ^ 1;
    const bool pref = (kt + 1 < nkt);
    char* KsC = (char*)(Ks + cur * 8192);
    char* VtC = (char*)(Vt + cur * 8192);

    // ---- issue prefetch for tile kt+1 ----
    if (pref){
      const size_t kvb = hb + (size_t)((kt + 1) * 64) * 2048;
      char* KsN = (char*)(Ks + nxt * 8192);
#pragma unroll
      for (int c = 0; c < 2; ++c){
        int off = c * 8192 + tid * 16;
        int row = off >> 8, colb = off & 255;
        gload_lds16((const char*)(K + kvb + (size_t)row * 2048) + (colb ^ ((row & 15) << 4)),
                    KsN + c * 8192 + (tid >> 6) * 1024 + (tid & 63) * 16);
      }
      const unsigned short* vp = V + kvb + (size_t)(2 * kvp) * 2048 + dblk * 8;
      r0 = *(const u16x8*)vp; r1 = *(const u16x8*)(vp + 2048);
    }

    // ---- compute tile kt from buffers [cur] ----
    if (!(kt * 64 > qw + 31)){
      f32x16 sacc[2];
#pragma unroll
      for (int sub = 0; sub < 2; ++sub){
#pragma unroll
        for (int j = 0; j < 16; ++j) sacc[sub][j] = 0.f;
        const int row = sub * 32 + lq;
        const int swz = (row & 15) << 4;
#pragma unroll
        for (int ks = 0; ks < 8; ++ks){
          bf16x8 kf = *(const bf16x8*)(KsC + row * 256 + ((ks * 32 + hi * 16) ^ swz));
          sacc[sub] = __builtin_amdgcn_mfma_f32_32x32x16_bf16(kf, qf[ks], sacc[sub], 0, 0, 0);
        }
      }

      float s[32];
#pragma unroll
      for (int sub = 0; sub < 2; ++sub)
#pragma unroll
        for (int r = 0; r < 16; ++r) s[sub * 16 + r] = sacc[sub][r];

      if (kt * 64 + 63 > qw){
        const int qg = qw + lq;
#pragma unroll
        for (int sub = 0; sub < 2; ++sub)
#pragma unroll
          for (int r = 0; r < 16; ++r){
            int kvg = kt * 64 + sub * 32 + (r & 3) + 8 * (r >> 2) + 4 * hi;
            if (kvg > qg) s[sub * 16 + r] = -3.0e38f;
          }
      }

      float mx[32];
#pragma unroll
      for (int i = 0; i < 32; ++i) mx[i] = s[i];
#pragma unroll
      for (int st = 1; st < 32; st <<= 1)
#pragma unroll
        for (int i = 0; i < 32; i += 2 * st) mx[i] = fmaxf(mx[i], mx[i + st]);
      float pmax = mx[0];
      pmax = fmaxf(pmax, __shfl_xor(pmax, 32, 64));

      // defer-max (T13): skip rescale when max growth <= 8 log2-units
      float mm;
      if (__all((pmax - mrow) * c2 <= 8.0f)){
        mm = mrow * c2;
      } else {
        float mnew = fmaxf(mrow, pmax);
        mm = mnew * c2;
        float corr = __builtin_amdgcn_exp2f(__builtin_fmaf(mrow, c2, -mm));
        mrow = mnew;
        lrow *= corr;
#pragma unroll
        for (int i = 0; i < 4; ++i)
#pragma unroll
          for (int j = 0; j < 16; ++j) oacc[i][j] *= corr;
      }

      float p[32];
#pragma unroll
      for (int i = 0; i < 32; ++i)
        p[i] = __builtin_amdgcn_exp2f(__builtin_fmaf(s[i], c2, -mm));
      float sm[32];
#pragma unroll
      for (int i = 0; i < 32; ++i) sm[i] = p[i];
#pragma unroll
      for (int st = 1; st < 32; st <<= 1)
#pragma unroll
        for (int i = 0; i < 32; i += 2 * st) sm[i] += sm[i + st];
      float rs = sm[0];
      rs += __shfl_xor(rs, 32, 64);
      lrow += rs;

      unsigned wv[16];
#pragma unroll
      for (int i = 0; i < 16; ++i) wv[i] = cvtpk(p[2 * i], p[2 * i + 1]);
      swap32(wv[0], wv[2]);   swap32(wv[1], wv[3]);
      swap32(wv[4], wv[6]);   swap32(wv[5], wv[7]);
      swap32(wv[8], wv[10]);  swap32(wv[9], wv[11]);
      swap32(wv[12], wv[14]); swap32(wv[13], wv[15]);

#pragma unroll
      for (int c = 0; c < 4; ++c){
        union { unsigned u[4]; bf16x8 v; } pu;
        pu.u[0] = wv[c * 4 + 0]; pu.u[1] = wv[c * 4 + 1];
        pu.u[2] = wv[c * 4 + 2]; pu.u[3] = wv[c * 4 + 3];
#pragma unroll
        for (int db = 0; db < 4; ++db){
          const int d = db * 32 + lq;
          bf16x8 vf = *(const bf16x8*)(VtC + d * 128 + ((c * 32 + hi * 16) ^ ((d & 7) << 4)));
          oacc[db] = __builtin_amdgcn_mfma_f32_32x32x16_bf16(vf, pu.v, oacc[db], 0, 0, 0);
        }
      }
    }

    // ---- complete prefetch: wait loads, pack V into [nxt] ----
    if (pref){
      asm volatile("s_waitcnt vmcnt(0)" ::: "memory");
      char* VtN = (char*)(Vt + nxt * 8192);
#pragma unroll
      for (int j = 0; j < 8; ++j){
        int d = dblk * 8 + j;
        unsigned val = (unsigned)r0[j] | ((unsigned)r1[j] << 16);
        *(unsigned*)(VtN + d * 128 + ((4 * kvp) ^ ((d & 7) << 4))) = val;
      }
    }
    __syncthreads();
  }

  // ---- epilogue: normalize, transpose O^T -> O via LDS, coalesced store ----
  float inv = 1.0f / lrow;
  char* lb = (char*)SMEM + wid * 8192;
#pragma unroll
  for (int db = 0; db < 4; ++db)
#pragma unroll
    for (int r = 0; r < 16; r += 2){
      int d = db * 32 + (r & 3) + 8 * (r >> 2) + 4 * hi;
      unsigned val = (unsigned)f2bf(oacc[db][r] * inv) |
                     ((unsigned)f2bf(oacc[db][r + 1] * inv) << 16);
      *(unsigned*)(lb + lq * 256 + ((2 * d) ^ ((lq & 7) << 4))) = val;
    }
  __syncthreads();
#pragma unroll
  for (int i = 0; i < 8; ++i){
    int rowq = i * 4 + (l >> 4);
    u16x8 vv = *(const u16x8*)(lb + rowq * 256 + (((l & 15) * 16) ^ ((rowq & 7) << 4)));
    *(u16x8*)(O + ((size_t)(b * 2048 + qw + rowq)) * 2048 + (size_t)h * 128 + (l & 15) * 8) = vv;
  }
}

// ---------------- host-side launch ----------------
extern "C" void kernel_launch(void* const* d_in, const int* in_sizes, int n_in,
                              void* d_out, int out_size, void* d_ws, size_t ws_size,
                              hipStream_t stream){
  const float* x  = (const float*)d_in[0];
  const float* wq = (const float*)d_in[1];
  const float* wk = (const float*)d_in[2];
  const float* wv = (const float*)d_in[3];
  const float* wo = (const float*)d_in[4];
  const float* fc = (const float*)d_in[5];
  const float* fs = (const float*)d_in[6];
  float* out = (float*)d_out;
  (void)in_sizes; (void)n_in; (void)out_size; (void)ws_size;

  const size_t XN = (size_t)8192 * 2048;
  const size_t WN = (size_t)2048 * 2048;

  unsigned short* xb  = (unsigned short*)d_ws;
  unsigned short* wqb = xb + XN;
  unsigned short* wkb = wqb + WN;
  unsigned short* wvb = wkb + WN;
  unsigned short* wob = wvb + WN;
  unsigned short* q   = wob + WN;
  unsigned short* k   = q + XN;
  unsigned short* v   = k + XN;
  unsigned short* att = xb;                // alias: x-bf16 dead after QKV GEMMs

  cvt_f32_bf16<<<dim3((unsigned)(XN / 1024)), 256, 0, stream>>>(x, xb);
  cvt_f32_bf16<<<dim3((unsigned)(WN / 1024)), 256, 0, stream>>>(wq, wqb);
  cvt_f32_bf16<<<dim3((unsigned)(WN / 1024)), 256, 0, stream>>>(wk, wkb);
  cvt_f32_bf16<<<dim3((unsigned)(WN / 1024)), 256, 0, stream>>>(wv, wvb);
  cvt_f32_bf16<<<dim3((unsigned)(WN / 1024)), 256, 0, stream>>>(wo, wob);

  gemm256<true><<<dim3(256), 512, 0, stream>>>(xb, wqb, q, 8192, 2048, 2048);
  gemm256<true><<<dim3(256), 512, 0, stream>>>(xb, wkb, k, 8192, 2048, 2048);
  gemm256<true><<<dim3(256), 512, 0, stream>>>(xb, wvb, v, 8192, 2048, 2048);

  rope_kernel<<<dim3(8192), 256, 0, stream>>>(q, k, fc, fs);

  attn_fwd<<<dim3(512), 512, 0, stream>>>(q, k, v, att);

  gemm256<false><<<dim3(256), 512, 0, stream>>>(att, wob, out, 8192, 2048, 2048);
}